// Round 14
// baseline (183.046 us; speedup 1.0000x reference)
//
#include <hip/hip_runtime.h>
#include <hip/hip_fp16.h>

#define N_NODES 50000
#define N_EDGES 800000
#define FDIM 64
#define N_GRAPHS 500
#define OUTF 10
#define SENT N_NODES
#define ROWCAP 64                       // fixed CSR row capacity; Poisson(16), P(deg>64)~1e-18
#define FILLB 2048
#define SEGB ((N_NODES + 256) / 256)    // 196

struct __align__(8) H4 { __half2 a, b; };

__device__ __forceinline__ float rl(float v, int l) {
    return __int_as_float(__builtin_amdgcn_readlane(__float_as_int(v), l));
}

// ---------------- single-pass CSR build (deg doubles as cursor) + seg starts ----------------
// XCD affinity: owner(node)=(n>>5)&7, block proxy = blockIdx&7 (heuristic only;
// every edge is handled by exactly one block regardless of placement).
__global__ __launch_bounds__(256) void fill_seg(
    const int* __restrict__ src, const int* __restrict__ dst,
    int* __restrict__ deg, int* __restrict__ csr,
    const int* __restrict__ batch, int* __restrict__ start) {
    int bid = blockIdx.x;
    if (bid < FILLB) {
        int myx = bid & 7, cid = bid >> 3, nch = FILLB >> 3;
        for (int e = cid * 256 + threadIdx.x; e < N_EDGES; e += nch * 256) {
            int d = dst[e];
            if (((d >> 5) & 7) != myx) continue;
            int pos = atomicAdd(&deg[d], 1);
            if (pos < ROWCAP) csr[d * ROWCAP + pos] = src[e];
        }
    } else {
        int i = (bid - FILLB) * 256 + threadIdx.x;
        if (i > N_NODES) return;
        int b  = (i < N_NODES) ? batch[i] : N_GRAPHS;
        int bp = (i == 0) ? -1 : batch[i - 1];
        for (int g = bp + 1; g <= b; ++g) start[g] = i;
    }
}

// ---------------- dinv + prescale x -> fp16, + zero sentinel rows ----------------
__global__ __launch_bounds__(256) void prescale(
    const int* __restrict__ deg, const float* __restrict__ x,
    float* __restrict__ dinv, __half* __restrict__ hsx, __half* __restrict__ hs1) {
    if (blockIdx.x == 0 && threadIdx.x < 2 * FDIM) {
        __half z = __float2half(0.f);
        if (threadIdx.x < FDIM) hsx[(size_t)N_NODES * FDIM + threadIdx.x] = z;
        else                    hs1[(size_t)N_NODES * FDIM + threadIdx.x - FDIM] = z;
    }
    __shared__ float sdinv[256];
    int i = blockIdx.x * 256 + threadIdx.x;
    int d = (i < N_NODES) ? deg[i] : 0;
    float dn = rsqrtf((float)d + 1.0f);      // +1 self-loop
    if (i < N_NODES) dinv[i] = dn;
    sdinv[threadIdx.x] = dn;
    __syncthreads();
    int n0 = blockIdx.x * 256;
    #pragma unroll 4
    for (int it = 0; it < 16; ++it) {
        int gid = (n0 << 4) + it * 256 + threadIdx.x;   // float4 index
        int n = gid >> 4;
        if (n >= N_NODES) break;
        float s = sdinv[n - n0];
        float4 vv = ((const float4*)x)[gid];
        H4 o;
        o.a = __floats2half2_rn(vv.x * s, vv.y * s);
        o.b = __floats2half2_rn(vv.z * s, vv.w * s);
        ((H4*)hsx)[gid] = o;
    }
}

// ---------------- fused GCN layer: 4 nodes/wave, 16 lanes/node ----------------
// csr indices fetched as 2x int4 per 8-edge batch (rows are 16B-aligned, padded
// to 64 ints); pad garbage is masked to SENT *before* the feature load, so no
// clamp needed. pk_f16 dual-chain accumulation, fp32 combine + matvec.
template <bool SCALE_OUT>
__global__ __launch_bounds__(256) void gcn_fused(
    const int* __restrict__ deg, const int* __restrict__ csr,
    const float* __restrict__ dinv, const __half* __restrict__ hs,
    const float* __restrict__ W, const float* __restrict__ bias,
    __half* __restrict__ out) {
    __shared__ float Ws[FDIM * FDIM];
    int tid = threadIdx.x;
    int lane = tid & 63;
    int L = lane & 15, q = lane >> 4;
    int nodeBase = (blockIdx.x * 4 + (tid >> 6)) * 4;   // grid = 3125 exact
    int myN = nodeBase + q;

    float dn = dinv[myN];
    int d = min(deg[myN], ROWCAP);
    int row = myN << 6;                      // myN * ROWCAP
    int dpad = (d + 7) & ~7;

    H4 sv = *(const H4*)(hs + (size_t)myN * FDIM + 4 * L);  // self term
    __half2 z2 = __floats2half2_rn(0.f, 0.f);
    __half2 c0a = sv.a, c0b = sv.b;          // chain 0 seeded with self term
    __half2 c1a = z2,   c1b = z2;            // chain 1

    #pragma unroll
    for (int i = 0; i < 16; ++i) Ws[tid + i * 256] = W[tid + i * 256];
    __syncthreads();

    for (int base = 0; base < dpad; base += 8) {
        int4 sA = *(const int4*)(csr + row + base);      // broadcast 16B
        int4 sB = *(const int4*)(csr + row + base + 4);
        int ss[8] = { sA.x, sA.y, sA.z, sA.w, sB.x, sB.y, sB.z, sB.w };
        #pragma unroll
        for (int j = 0; j < 8; ++j) {
            int e = base + j;
            int s = (e < d) ? ss[j] : SENT;  // mask pad garbage BEFORE the load
            H4 hv = *(const H4*)(hs + (size_t)s * FDIM + 4 * L);
            if (j & 1) { c1a = __hadd2(c1a, hv.a); c1b = __hadd2(c1b, hv.b); }
            else       { c0a = __hadd2(c0a, hv.a); c0b = __hadd2(c0b, hv.b); }
        }
    }
    // combine chains in fp32, scale by dinv
    float2 t0a = __half22float2(c0a), t1a = __half22float2(c1a);
    float2 t0b = __half22float2(c0b), t1b = __half22float2(c1b);
    float4 acc = make_float4((t0a.x + t1a.x) * dn, (t0a.y + t1a.y) * dn,
                             (t0b.x + t1b.x) * dn, (t0b.y + t1b.y) * dn);

    float b0 = bias[lane];
    float o0 = b0, o1 = b0, o2 = b0, o3 = b0;
    #pragma unroll
    for (int k = 0; k < 64; ++k) {
        float wv = Ws[k * 64 + lane];
        int sl = k >> 2;
        float comp = (k & 3) == 0 ? acc.x : (k & 3) == 1 ? acc.y : (k & 3) == 2 ? acc.z : acc.w;
        o0 = fmaf(rl(comp, sl),      wv, o0);
        o1 = fmaf(rl(comp, sl + 16), wv, o1);
        o2 = fmaf(rl(comp, sl + 32), wv, o2);
        o3 = fmaf(rl(comp, sl + 48), wv, o3);
    }
    o0 = fmaxf(o0, 0.f); o1 = fmaxf(o1, 0.f); o2 = fmaxf(o2, 0.f); o3 = fmaxf(o3, 0.f);
    if (SCALE_OUT) {   // pre-scale rows by dinv for the next layer's gather
        o0 *= rl(dn, 0); o1 *= rl(dn, 16); o2 *= rl(dn, 32); o3 *= rl(dn, 48);
    }
    out[(size_t)(nodeBase + 0) * FDIM + lane] = __float2half_rn(o0);
    out[(size_t)(nodeBase + 1) * FDIM + lane] = __float2half_rn(o1);
    out[(size_t)(nodeBase + 2) * FDIM + lane] = __float2half_rn(o2);
    out[(size_t)(nodeBase + 3) * FDIM + lane] = __float2half_rn(o3);
}

// ---------------- fused mean-pool + head + log_softmax (fp16 input) ----------------
__global__ __launch_bounds__(256) void pool_head(
    const __half* __restrict__ h, const int* __restrict__ start,
    const float* __restrict__ Wc, const float* __restrict__ bc,
    float* __restrict__ out) {
    int g = blockIdx.x;
    int tid = threadIdx.x;
    int lane = tid & 63, w = tid >> 6;
    int L = lane & 15, q = lane >> 4;
    int s0 = start[g], s1 = start[g + 1];
    int sub = w * 4 + q;

    float4 acc = make_float4(0.f, 0.f, 0.f, 0.f);
    for (int i = s0 + sub; i < s1; i += 16) {
        H4 hv = *(const H4*)(h + (size_t)i * FDIM + 4 * L);
        float2 lo = __half22float2(hv.a), hi = __half22float2(hv.b);
        acc.x += lo.x; acc.y += lo.y; acc.z += hi.x; acc.w += hi.y;
    }
    #pragma unroll
    for (int m = 16; m <= 32; m <<= 1) {
        acc.x += __shfl_xor(acc.x, m);
        acc.y += __shfl_xor(acc.y, m);
        acc.z += __shfl_xor(acc.z, m);
        acc.w += __shfl_xor(acc.w, m);
    }
    __shared__ float ps[4 * 64];
    __shared__ float pm[64];
    __shared__ float logits[OUTF];
    if (q == 0) *(float4*)(ps + w * 64 + 4 * L) = acc;
    __syncthreads();
    if (tid < 64) {
        float tot = ps[tid] + ps[64 + tid] + ps[128 + tid] + ps[192 + tid];
        float c = (float)((s1 - s0) > 1 ? (s1 - s0) : 1);
        pm[tid] = tot / c;
    }
    __syncthreads();
    if (tid < OUTF) {
        float a = bc[tid];
        #pragma unroll
        for (int k = 0; k < 64; ++k) a = fmaf(pm[k], Wc[k * OUTF + tid], a);
        logits[tid] = a;
    }
    __syncthreads();
    if (tid == 0) {
        float m = -1e30f;
        #pragma unroll
        for (int i = 0; i < OUTF; ++i) m = fmaxf(m, logits[i]);
        float s = 0.f;
        #pragma unroll
        for (int i = 0; i < OUTF; ++i) s += __expf(logits[i] - m);
        float lse = m + __logf(s);
        #pragma unroll
        for (int i = 0; i < OUTF; ++i) out[g * OUTF + i] = logits[i] - lse;
    }
}

extern "C" void kernel_launch(void* const* d_in, const int* in_sizes, int n_in,
                              void* d_out, int out_size, void* d_ws, size_t ws_size,
                              hipStream_t stream) {
    const float* x     = (const float*)d_in[0];
    const int*   ei    = (const int*)d_in[1];
    const int*   batch = (const int*)d_in[2];
    const float* W1    = (const float*)d_in[3];
    const float* b1    = (const float*)d_in[4];
    const float* W2    = (const float*)d_in[5];
    const float* b2    = (const float*)d_in[6];
    const float* Wc    = (const float*)d_in[7];
    const float* bc    = (const float*)d_in[8];
    float* out = (float*)d_out;

    const int* src = ei;
    const int* dst = ei + N_EDGES;

    // workspace layout (int units); csr base is 16B-aligned (offset 100504 ints)
    int*    ws    = (int*)d_ws;
    int*    deg   = ws;                                  // 50000 (memset to 0)
    float*  dinv  = (float*)(deg + N_NODES);             // 50000
    int*    start = (int*)(dinv + N_NODES);              // 504
    int*    csr   = start + N_GRAPHS + 4;                // 50000*64 = 3.2M ints
    __half* hsx   = (__half*)(csr + N_NODES * ROWCAP);   // (N_NODES+1)*64 halves
    __half* hs1   = hsx + (size_t)(N_NODES + 1) * FDIM;

    hipMemsetAsync(deg, 0, N_NODES * sizeof(int), stream);

    fill_seg <<<FILLB + SEGB, 256, 0, stream>>>(src, dst, deg, csr, batch, start);
    prescale <<<(N_NODES + 255) / 256, 256, 0, stream>>>(deg, x, dinv, hsx, hs1);

    const int gcnGrid = N_NODES / 16;  // 3125 exact
    gcn_fused<true ><<<gcnGrid, 256, 0, stream>>>(deg, csr, dinv, hsx, W1, b1, hs1);
    gcn_fused<false><<<gcnGrid, 256, 0, stream>>>(deg, csr, dinv, hs1, W2, b2, hsx);

    pool_head<<<N_GRAPHS, 256, 0, stream>>>(hsx, start, Wc, bc, out);
}

// Round 15
// 181.494 us; speedup vs baseline: 1.0086x; 1.0086x over previous
//
#include <hip/hip_runtime.h>
#include <hip/hip_fp16.h>

#define N_NODES 50000
#define N_EDGES 800000
#define FDIM 64
#define N_GRAPHS 500
#define OUTF 10
#define SENT N_NODES
#define ROWCAP 64                       // fixed CSR row capacity; Poisson(16), P(deg>64)~1e-18
#define FILLB 4096
#define SEGB ((N_NODES + 256) / 256)    // 196

struct __align__(8) H4 { __half2 a, b; };

__device__ __forceinline__ float rl(float v, int l) {
    return __int_as_float(__builtin_amdgcn_readlane(__float_as_int(v), l));
}

// ---------------- single-pass CSR build (deg doubles as cursor) + seg starts ----------------
// XCD affinity: owner(node)=(n>>5)&7, block proxy = blockIdx&7 (heuristic only;
// every edge is handled by exactly one block regardless of placement).
__global__ __launch_bounds__(256) void fill_seg(
    const int* __restrict__ src, const int* __restrict__ dst,
    int* __restrict__ deg, int* __restrict__ csr,
    const int* __restrict__ batch, int* __restrict__ start) {
    int bid = blockIdx.x;
    if (bid < FILLB) {
        int myx = bid & 7, cid = bid >> 3, nch = FILLB >> 3;
        for (int e = cid * 256 + threadIdx.x; e < N_EDGES; e += nch * 256) {
            int d = dst[e];
            if (((d >> 5) & 7) != myx) continue;
            int pos = atomicAdd(&deg[d], 1);
            if (pos < ROWCAP) csr[d * ROWCAP + pos] = src[e];
        }
    } else {
        int i = (bid - FILLB) * 256 + threadIdx.x;
        if (i > N_NODES) return;
        int b  = (i < N_NODES) ? batch[i] : N_GRAPHS;
        int bp = (i == 0) ? -1 : batch[i - 1];
        for (int g = bp + 1; g <= b; ++g) start[g] = i;
    }
}

// ---------------- dinv + prescale x -> fp16, + zero sentinel rows ----------------
__global__ __launch_bounds__(256) void prescale(
    const int* __restrict__ deg, const float* __restrict__ x,
    float* __restrict__ dinv, __half* __restrict__ hsx, __half* __restrict__ hs1) {
    if (blockIdx.x == 0 && threadIdx.x < 2 * FDIM) {
        __half z = __float2half(0.f);
        if (threadIdx.x < FDIM) hsx[(size_t)N_NODES * FDIM + threadIdx.x] = z;
        else                    hs1[(size_t)N_NODES * FDIM + threadIdx.x - FDIM] = z;
    }
    __shared__ float sdinv[256];
    int i = blockIdx.x * 256 + threadIdx.x;
    int d = (i < N_NODES) ? deg[i] : 0;
    float dn = rsqrtf((float)d + 1.0f);      // +1 self-loop
    if (i < N_NODES) dinv[i] = dn;
    sdinv[threadIdx.x] = dn;
    __syncthreads();
    int n0 = blockIdx.x * 256;
    #pragma unroll 4
    for (int it = 0; it < 16; ++it) {
        int gid = (n0 << 4) + it * 256 + threadIdx.x;   // float4 index
        int n = gid >> 4;
        if (n >= N_NODES) break;
        float s = sdinv[n - n0];
        float4 vv = ((const float4*)x)[gid];
        H4 o;
        o.a = __floats2half2_rn(vv.x * s, vv.y * s);
        o.b = __floats2half2_rn(vv.z * s, vv.w * s);
        ((H4*)hsx)[gid] = o;
    }
}

// ---------------- fused GCN layer: 4 nodes/wave, 16 lanes/node ----------------
// csr indices double-buffered: next batch's 2x int4 issued BEFORE this batch's
// feature loads (overlaps index latency with feature latency). Prefetch clamps
// to min(base+8,56) -> always inside the node's fixed 64-int row; pad garbage
// masked to SENT before the feature load. pk_f16 dual-chain accumulation.
template <bool SCALE_OUT>
__global__ __launch_bounds__(256) void gcn_fused(
    const int* __restrict__ deg, const int* __restrict__ csr,
    const float* __restrict__ dinv, const __half* __restrict__ hs,
    const float* __restrict__ W, const float* __restrict__ bias,
    __half* __restrict__ out) {
    __shared__ float Ws[FDIM * FDIM];
    int tid = threadIdx.x;
    int lane = tid & 63;
    int L = lane & 15, q = lane >> 4;
    int nodeBase = (blockIdx.x * 4 + (tid >> 6)) * 4;   // grid = 3125 exact
    int myN = nodeBase + q;

    float dn = dinv[myN];
    int d = min(deg[myN], ROWCAP);
    int row = myN << 6;                      // myN * ROWCAP
    int dpad = (d + 7) & ~7;

    H4 sv = *(const H4*)(hs + (size_t)myN * FDIM + 4 * L);  // self term
    __half2 z2 = __floats2half2_rn(0.f, 0.f);
    __half2 c0a = sv.a, c0b = sv.b;          // chain 0 seeded with self term
    __half2 c1a = z2,   c1b = z2;            // chain 1

    #pragma unroll
    for (int i = 0; i < 16; ++i) Ws[tid + i * 256] = W[tid + i * 256];
    __syncthreads();

    int4 sA = *(const int4*)(csr + row);     // prime the index pipeline
    int4 sB = *(const int4*)(csr + row + 4);
    for (int base = 0; base < dpad; base += 8) {
        int nxt = min(base + 8, 56);         // stays inside this node's row
        int4 nA = *(const int4*)(csr + row + nxt);
        int4 nB = *(const int4*)(csr + row + nxt + 4);
        int ss[8] = { sA.x, sA.y, sA.z, sA.w, sB.x, sB.y, sB.z, sB.w };
        #pragma unroll
        for (int j = 0; j < 8; ++j) {
            int e = base + j;
            int s = (e < d) ? ss[j] : SENT;  // mask pad garbage BEFORE the load
            H4 hv = *(const H4*)(hs + (size_t)s * FDIM + 4 * L);
            if (j & 1) { c1a = __hadd2(c1a, hv.a); c1b = __hadd2(c1b, hv.b); }
            else       { c0a = __hadd2(c0a, hv.a); c0b = __hadd2(c0b, hv.b); }
        }
        sA = nA; sB = nB;
    }
    // combine chains in fp32, scale by dinv
    float2 t0a = __half22float2(c0a), t1a = __half22float2(c1a);
    float2 t0b = __half22float2(c0b), t1b = __half22float2(c1b);
    float4 acc = make_float4((t0a.x + t1a.x) * dn, (t0a.y + t1a.y) * dn,
                             (t0b.x + t1b.x) * dn, (t0b.y + t1b.y) * dn);

    float b0 = bias[lane];
    float o0 = b0, o1 = b0, o2 = b0, o3 = b0;
    #pragma unroll
    for (int k = 0; k < 64; ++k) {
        float wv = Ws[k * 64 + lane];
        int sl = k >> 2;
        float comp = (k & 3) == 0 ? acc.x : (k & 3) == 1 ? acc.y : (k & 3) == 2 ? acc.z : acc.w;
        o0 = fmaf(rl(comp, sl),      wv, o0);
        o1 = fmaf(rl(comp, sl + 16), wv, o1);
        o2 = fmaf(rl(comp, sl + 32), wv, o2);
        o3 = fmaf(rl(comp, sl + 48), wv, o3);
    }
    o0 = fmaxf(o0, 0.f); o1 = fmaxf(o1, 0.f); o2 = fmaxf(o2, 0.f); o3 = fmaxf(o3, 0.f);
    if (SCALE_OUT) {   // pre-scale rows by dinv for the next layer's gather
        o0 *= rl(dn, 0); o1 *= rl(dn, 16); o2 *= rl(dn, 32); o3 *= rl(dn, 48);
    }
    out[(size_t)(nodeBase + 0) * FDIM + lane] = __float2half_rn(o0);
    out[(size_t)(nodeBase + 1) * FDIM + lane] = __float2half_rn(o1);
    out[(size_t)(nodeBase + 2) * FDIM + lane] = __float2half_rn(o2);
    out[(size_t)(nodeBase + 3) * FDIM + lane] = __float2half_rn(o3);
}

// ---------------- fused mean-pool + head + log_softmax (fp16 input) ----------------
__global__ __launch_bounds__(256) void pool_head(
    const __half* __restrict__ h, const int* __restrict__ start,
    const float* __restrict__ Wc, const float* __restrict__ bc,
    float* __restrict__ out) {
    int g = blockIdx.x;
    int tid = threadIdx.x;
    int lane = tid & 63, w = tid >> 6;
    int L = lane & 15, q = lane >> 4;
    int s0 = start[g], s1 = start[g + 1];
    int sub = w * 4 + q;

    float4 acc = make_float4(0.f, 0.f, 0.f, 0.f);
    for (int i = s0 + sub; i < s1; i += 16) {
        H4 hv = *(const H4*)(h + (size_t)i * FDIM + 4 * L);
        float2 lo = __half22float2(hv.a), hi = __half22float2(hv.b);
        acc.x += lo.x; acc.y += lo.y; acc.z += hi.x; acc.w += hi.y;
    }
    #pragma unroll
    for (int m = 16; m <= 32; m <<= 1) {
        acc.x += __shfl_xor(acc.x, m);
        acc.y += __shfl_xor(acc.y, m);
        acc.z += __shfl_xor(acc.z, m);
        acc.w += __shfl_xor(acc.w, m);
    }
    __shared__ float ps[4 * 64];
    __shared__ float pm[64];
    __shared__ float logits[OUTF];
    if (q == 0) *(float4*)(ps + w * 64 + 4 * L) = acc;
    __syncthreads();
    if (tid < 64) {
        float tot = ps[tid] + ps[64 + tid] + ps[128 + tid] + ps[192 + tid];
        float c = (float)((s1 - s0) > 1 ? (s1 - s0) : 1);
        pm[tid] = tot / c;
    }
    __syncthreads();
    if (tid < OUTF) {
        float a = bc[tid];
        #pragma unroll
        for (int k = 0; k < 64; ++k) a = fmaf(pm[k], Wc[k * OUTF + tid], a);
        logits[tid] = a;
    }
    __syncthreads();
    if (tid == 0) {
        float m = -1e30f;
        #pragma unroll
        for (int i = 0; i < OUTF; ++i) m = fmaxf(m, logits[i]);
        float s = 0.f;
        #pragma unroll
        for (int i = 0; i < OUTF; ++i) s += __expf(logits[i] - m);
        float lse = m + __logf(s);
        #pragma unroll
        for (int i = 0; i < OUTF; ++i) out[g * OUTF + i] = logits[i] - lse;
    }
}

extern "C" void kernel_launch(void* const* d_in, const int* in_sizes, int n_in,
                              void* d_out, int out_size, void* d_ws, size_t ws_size,
                              hipStream_t stream) {
    const float* x     = (const float*)d_in[0];
    const int*   ei    = (const int*)d_in[1];
    const int*   batch = (const int*)d_in[2];
    const float* W1    = (const float*)d_in[3];
    const float* b1    = (const float*)d_in[4];
    const float* W2    = (const float*)d_in[5];
    const float* b2    = (const float*)d_in[6];
    const float* Wc    = (const float*)d_in[7];
    const float* bc    = (const float*)d_in[8];
    float* out = (float*)d_out;

    const int* src = ei;
    const int* dst = ei + N_EDGES;

    // workspace layout (int units); csr base is 16B-aligned (offset 100504 ints)
    int*    ws    = (int*)d_ws;
    int*    deg   = ws;                                  // 50000 (memset to 0)
    float*  dinv  = (float*)(deg + N_NODES);             // 50000
    int*    start = (int*)(dinv + N_NODES);              // 504
    int*    csr   = start + N_GRAPHS + 4;                // 50000*64 = 3.2M ints
    __half* hsx   = (__half*)(csr + N_NODES * ROWCAP);   // (N_NODES+1)*64 halves
    __half* hs1   = hsx + (size_t)(N_NODES + 1) * FDIM;

    hipMemsetAsync(deg, 0, N_NODES * sizeof(int), stream);

    fill_seg <<<FILLB + SEGB, 256, 0, stream>>>(src, dst, deg, csr, batch, start);
    prescale <<<(N_NODES + 255) / 256, 256, 0, stream>>>(deg, x, dinv, hsx, hs1);

    const int gcnGrid = N_NODES / 16;  // 3125 exact
    gcn_fused<true ><<<gcnGrid, 256, 0, stream>>>(deg, csr, dinv, hsx, W1, b1, hs1);
    gcn_fused<false><<<gcnGrid, 256, 0, stream>>>(deg, csr, dinv, hs1, W2, b2, hsx);

    pool_head<<<N_GRAPHS, 256, 0, stream>>>(hsx, start, Wc, bc, out);
}